// Round 1
// baseline (1770.218 us; speedup 1.0000x reference)
//
#include <hip/hip_runtime.h>
#include <hip/hip_bf16.h>
#include <math.h>

#define BB 8
#define LQ 900
#define EE 256
#define NH 8
#define HD 32
#define NL 4
#define NP 4
#define FFN_H 1024

// ---------------------------------------------------------------------------
// LayerNorm over E=256, one block (256 thr) per row.
// out_x = ln(in) (optional), out_xa = ln(in) + add (optional)
// ---------------------------------------------------------------------------
__global__ __launch_bounds__(256) void ln_kernel(
    const float* __restrict__ in, const float* __restrict__ s,
    const float* __restrict__ b, const float* __restrict__ add,
    float* __restrict__ out_x, float* __restrict__ out_xa)
{
    const int row = blockIdx.x;
    const int t = threadIdx.x;
    const int w = t >> 6;          // wave id (0..3)
    const int lane = t & 63;
    __shared__ float red[4];

    float v = in[(size_t)row * EE + t];

    float sum = v;
#pragma unroll
    for (int o = 32; o; o >>= 1) sum += __shfl_xor(sum, o, 64);
    if (lane == 0) red[w] = sum;
    __syncthreads();
    float mean = (red[0] + red[1] + red[2] + red[3]) * (1.0f / 256.0f);
    __syncthreads();

    float d = v - mean;
    float sq = d * d;
#pragma unroll
    for (int o = 32; o; o >>= 1) sq += __shfl_xor(sq, o, 64);
    if (lane == 0) red[w] = sq;
    __syncthreads();
    float var = (red[0] + red[1] + red[2] + red[3]) * (1.0f / 256.0f);

    float y = d * rsqrtf(var + 1e-5f) * s[t] + b[t];
    if (out_x)  out_x[(size_t)row * EE + t] = y;
    if (out_xa) out_xa[(size_t)row * EE + t] = y + add[(size_t)row * EE + t];
}

// ---------------------------------------------------------------------------
// Tiled fp32 GEMM: C[M,N] = act(A[M,K] @ W[K,N] + bias + resid)
// 64x64 tile, BK=16, 256 threads, 4x4 register blocking.
// act: 0 none, 1 relu, 2 sigmoid
// ---------------------------------------------------------------------------
__global__ __launch_bounds__(256) void gemm64(
    const float* __restrict__ A, const float* __restrict__ W,
    const float* __restrict__ bias, const float* __restrict__ resid,
    float* __restrict__ C, int M, int K, int N, int act)
{
    const int tid = threadIdx.x;
    const int tx = tid & 15;
    const int ty = tid >> 4;
    const int n0 = blockIdx.x * 64;
    const int m0 = blockIdx.y * 64;

    __shared__ float As[16][64];   // [k][m]
    __shared__ float Ws[16][64];   // [k][n]

    float acc[4][4] = {};

    const int lr = tid >> 2;            // 0..63 : row within A tile
    const int lc = (tid & 3) * 4;       // 0,4,8,12 : k offset
    const int wr = tid >> 4;            // 0..15 : k row of W tile
    const int wc = (tid & 15) * 4;      // col within W tile

    for (int k0 = 0; k0 < K; k0 += 16) {
        float4 a4;
        int gm = m0 + lr;
        if (gm < M) a4 = *(const float4*)&A[(size_t)gm * K + k0 + lc];
        else        a4 = make_float4(0.f, 0.f, 0.f, 0.f);
        As[lc + 0][lr] = a4.x;
        As[lc + 1][lr] = a4.y;
        As[lc + 2][lr] = a4.z;
        As[lc + 3][lr] = a4.w;

        float4 w4 = *(const float4*)&W[(size_t)(k0 + wr) * N + n0 + wc];
        *(float4*)&Ws[wr][wc] = w4;

        __syncthreads();
#pragma unroll
        for (int k = 0; k < 16; ++k) {
            const float4 av = *(const float4*)&As[k][ty * 4];
            const float4 wv = *(const float4*)&Ws[k][tx * 4];
            float a_[4] = {av.x, av.y, av.z, av.w};
            float w_[4] = {wv.x, wv.y, wv.z, wv.w};
#pragma unroll
            for (int i = 0; i < 4; ++i)
#pragma unroll
                for (int j = 0; j < 4; ++j)
                    acc[i][j] = fmaf(a_[i], w_[j], acc[i][j]);
        }
        __syncthreads();
    }

#pragma unroll
    for (int i = 0; i < 4; ++i) {
        int gm = m0 + ty * 4 + i;
        if (gm >= M) continue;
#pragma unroll
        for (int j = 0; j < 4; ++j) {
            int gn = n0 + tx * 4 + j;
            float v = acc[i][j];
            if (bias)  v += bias[gn];
            if (resid) v += resid[(size_t)gm * N + gn];
            if (act == 1)      v = fmaxf(v, 0.f);
            else if (act == 2) v = 1.0f / (1.0f + __expf(-v));
            C[(size_t)gm * N + gn] = v;
        }
    }
}

// ---------------------------------------------------------------------------
// Fused self-attention. grid = (ceil(LQ/8), B*NH), block = 256.
// Each 32-lane group owns one q row: scores in LDS, online softmax, PV.
// Q,K,V layout: [B*LQ][256] with head slice h*32..h*32+31.
// out: attnV [B*LQ][256]
// ---------------------------------------------------------------------------
__global__ __launch_bounds__(256) void attn_kernel(
    const float* __restrict__ Q, const float* __restrict__ Kb,
    const float* __restrict__ V, float* __restrict__ out)
{
    const int bh = blockIdx.y;
    const int b = bh / NH, h = bh % NH;
    const int q0 = blockIdx.x * 8;
    const int t = threadIdx.x;
    const int g = t >> 5, lane = t & 31;
    const int q = q0 + g;

    __shared__ float sc[8][LQ];

    if (q >= LQ) return;

    const float scale = 0.17677669529663689f;  // 1/sqrt(32)

    float4 qv[8];
    {
        const float4* qp = (const float4*)&Q[((size_t)b * LQ + q) * EE + h * HD];
#pragma unroll
        for (int i = 0; i < 8; ++i) qv[i] = qp[i];
    }

    for (int k = lane; k < LQ; k += 32) {
        const float4* kp = (const float4*)&Kb[((size_t)b * LQ + k) * EE + h * HD];
        float sdot = 0.f;
#pragma unroll
        for (int i = 0; i < 8; ++i) {
            float4 kv = kp[i];
            sdot += qv[i].x * kv.x + qv[i].y * kv.y + qv[i].z * kv.z + qv[i].w * kv.w;
        }
        sc[g][k] = sdot * scale;
    }

    // softmax over this group's row (no cross-group sharing -> wave lockstep)
    float mloc = -1e30f;
    for (int k = lane; k < LQ; k += 32) mloc = fmaxf(mloc, sc[g][k]);
#pragma unroll
    for (int o = 16; o; o >>= 1) mloc = fmaxf(mloc, __shfl_xor(mloc, o, 32));
    float ssum = 0.f;
    for (int k = lane; k < LQ; k += 32) {
        float e = __expf(sc[g][k] - mloc);
        sc[g][k] = e;
        ssum += e;
    }
#pragma unroll
    for (int o = 16; o; o >>= 1) ssum += __shfl_xor(ssum, o, 32);
    float inv = 1.0f / ssum;

    // PV: lane = head dim
    const float* vp = &V[(size_t)b * LQ * EE + h * HD + lane];
    float a0 = 0.f;
#pragma unroll 4
    for (int k = 0; k < LQ; ++k) a0 += sc[g][k] * vp[(size_t)k * EE];

    out[((size_t)b * LQ + q) * EE + h * HD + lane] = a0 * inv;
}

// ---------------------------------------------------------------------------
// Sampling-weight softmax (over 16 per head) + sampling locations.
// grid = B*LQ, block = 256.
// ---------------------------------------------------------------------------
__global__ __launch_bounds__(256) void locaw_kernel(
    const float* __restrict__ att, const float* __restrict__ off,
    const float* __restrict__ refp, float* __restrict__ aw_out,
    float* __restrict__ loc_out)
{
    const int row = blockIdx.x;
    const int t = threadIdx.x;
    __shared__ float a_l[128];
    if (t < 128) a_l[t] = att[(size_t)row * 128 + t];
    __syncthreads();
    if (t < 128) {
        int h = t >> 4;
        float mx = -1e30f;
#pragma unroll
        for (int i = 0; i < 16; ++i) mx = fmaxf(mx, a_l[h * 16 + i]);
        float sum = 0.f;
#pragma unroll
        for (int i = 0; i < 16; ++i) sum += __expf(a_l[h * 16 + i] - mx);
        aw_out[(size_t)row * 128 + t] = __expf(a_l[t] - mx) / sum;
    }
    // loc: t = ((h*4 + l)*4 + p)*2 + c
    float o = off[(size_t)row * 256 + t];
    int c = t & 1;
    int l = (t >> 3) & 3;
    float rc = refp[((size_t)row * 4 + l) * 4 + c];
    float rs = refp[((size_t)row * 4 + l) * 4 + 2 + c];
    loc_out[(size_t)row * 256 + t] = rc + o * 0.125f * rs;  // off/4 * rs * 0.5
}

// ---------------------------------------------------------------------------
// Deformable bilinear sampling. grid = B*LQ, block = 256 (h = t/32, d = t%32).
// val layout: [B*NV][256] row-major (head slice h*32+d).
// ---------------------------------------------------------------------------
__global__ __launch_bounds__(256) void sample_kernel(
    const float* __restrict__ val, const float* __restrict__ aw,
    const float* __restrict__ loc, const int* __restrict__ shapes,
    const int* __restrict__ starts, float* __restrict__ samp, int NV)
{
    const int row = blockIdx.x;
    const int b = row / LQ;
    const int t = threadIdx.x;
    const int h = t >> 5, d = t & 31;

    __shared__ float l_loc[256];
    __shared__ float l_aw[128];
    __shared__ int l_sh[NL * 2];
    __shared__ int l_st[NL];

    l_loc[t] = loc[(size_t)row * 256 + t];
    if (t < 128) l_aw[t] = aw[(size_t)row * 128 + t];
    if (t < NL * 2) l_sh[t] = shapes[t];
    if (t < NL) l_st[t] = starts[t];
    __syncthreads();

    float acc = 0.f;
    const float* vb = val + (size_t)b * NV * EE + h * HD + d;

#pragma unroll
    for (int l = 0; l < NL; ++l) {
        const int Hh = l_sh[l * 2], Ww = l_sh[l * 2 + 1];
        const int s0 = l_st[l];
#pragma unroll
        for (int p = 0; p < NP; ++p) {
            const int base = ((h * NL + l) * NP + p) * 2;
            float lx = l_loc[base], ly = l_loc[base + 1];
            float w = l_aw[h * 16 + l * NP + p];
            float px = lx * (float)Ww - 0.5f;
            float py = ly * (float)Hh - 0.5f;
            float x0f = floorf(px), y0f = floorf(py);
            float wx = px - x0f, wy = py - y0f;
            int x0 = (int)x0f, y0 = (int)y0f;
#pragma unroll
            for (int dy = 0; dy < 2; ++dy) {
                int yi = y0 + dy;
                bool vy = (yi >= 0) && (yi < Hh);
                int yc = min(max(yi, 0), Hh - 1);
                float wyv = dy ? wy : 1.f - wy;
#pragma unroll
                for (int dx = 0; dx < 2; ++dx) {
                    int xi = x0 + dx;
                    bool vv = vy && (xi >= 0) && (xi < Ww);
                    int xc = min(max(xi, 0), Ww - 1);
                    float wgt = w * wyv * (dx ? wx : 1.f - wx);
                    float gv = vb[(size_t)(s0 + yc * Ww + xc) * EE];
                    acc += vv ? wgt * gv : 0.f;
                }
            }
        }
    }
    samp[(size_t)row * EE + t] = acc;
}

// ---------------------------------------------------------------------------
// Gated fusion: x2 = g[:,:256]*x1 + g[:,256:]*cross
// ---------------------------------------------------------------------------
__global__ __launch_bounds__(256) void gate_kernel(
    const float* __restrict__ g, const float* __restrict__ x1,
    const float* __restrict__ cross, float* __restrict__ x2, int total)
{
    int i = blockIdx.x * 256 + threadIdx.x;
    if (i < total) {
        int row = i >> 8, e = i & 255;
        float g1 = g[(size_t)row * 512 + e];
        float g2 = g[(size_t)row * 512 + 256 + e];
        x2[i] = g1 * x1[i] + g2 * cross[i];
    }
}

// ---------------------------------------------------------------------------
extern "C" void kernel_launch(void* const* d_in, const int* in_sizes, int n_in,
                              void* d_out, int out_size, void* d_ws, size_t ws_size,
                              hipStream_t stream)
{
    const float* queries   = (const float*)d_in[0];
    const float* memory    = (const float*)d_in[1];
    const float* query_pos = (const float*)d_in[2];
    const float* refp      = (const float*)d_in[3];
    const int*   shapes    = (const int*)d_in[4];
    const int*   starts    = (const int*)d_in[5];
    const float* Wq  = (const float*)d_in[6],  *bq  = (const float*)d_in[7];
    const float* Wk  = (const float*)d_in[8],  *bk  = (const float*)d_in[9];
    const float* Wv  = (const float*)d_in[10], *bv  = (const float*)d_in[11];
    const float* Wo  = (const float*)d_in[12], *bo  = (const float*)d_in[13];
    const float* Wvd = (const float*)d_in[14], *bvd = (const float*)d_in[15];
    const float* Woff= (const float*)d_in[16], *boff= (const float*)d_in[17];
    const float* Watt= (const float*)d_in[18], *batt= (const float*)d_in[19];
    const float* Wop = (const float*)d_in[20], *bop = (const float*)d_in[21];
    const float* Wg  = (const float*)d_in[22], *bg  = (const float*)d_in[23];
    const float* W1  = (const float*)d_in[24], *b1  = (const float*)d_in[25];
    const float* W2  = (const float*)d_in[26], *b2  = (const float*)d_in[27];
    const float* ln1_s = (const float*)d_in[28], *ln1_b = (const float*)d_in[29];
    const float* ln2_s = (const float*)d_in[30], *ln2_b = (const float*)d_in[31];
    const float* ln3_s = (const float*)d_in[32], *ln3_b = (const float*)d_in[33];

    const int NV = in_sizes[1] / (BB * EE);   // 13294
    const int Mq = BB * LQ;                   // 7200

    float* ws = (float*)d_ws;
    const size_t S = (size_t)BB * LQ * EE;    // 1,843,200
    float* buf0 = ws;           // x -> attnV -> off_tmp -> z
    float* buf1 = ws + S;       // qk -> qc
    float* buf2 = ws + 2 * S;   // Q -> att_tmp -> samp
    float* buf3 = ws + 3 * S;   // K -> cross
    float* buf4 = ws + 4 * S;   // V -> x2
    float* buf5 = ws + 5 * S;   // x1
    float* bufG = ws + 6 * S;   // g (2S) then ffn hidden (4S)
    float* bufVal = ws + 10 * S; // val [B*NV][256]

    float* out0    = (float*)d_out;
    float* aw_out  = out0 + S;
    float* loc_out = aw_out + (size_t)BB * LQ * 128;

    dim3 blk(256);

    // val = memory @ Wvd + bvd  (independent, launch first)
    gemm64<<<dim3(EE / 64, (BB * NV + 63) / 64), blk, 0, stream>>>(
        memory, Wvd, bvd, nullptr, bufVal, BB * NV, EE, EE, 0);

    // ln1: x = ln(queries), qk = x + query_pos
    ln_kernel<<<Mq, blk, 0, stream>>>(queries, ln1_s, ln1_b, query_pos, buf0, buf1);

    // Q, K, V
    dim3 gq(EE / 64, (Mq + 63) / 64);
    gemm64<<<gq, blk, 0, stream>>>(buf1, Wq, bq, nullptr, buf2, Mq, EE, EE, 0);
    gemm64<<<gq, blk, 0, stream>>>(buf1, Wk, bk, nullptr, buf3, Mq, EE, EE, 0);
    gemm64<<<gq, blk, 0, stream>>>(buf0, Wv, bv, nullptr, buf4, Mq, EE, EE, 0);

    // self-attention -> attnV (buf0)
    attn_kernel<<<dim3((LQ + 7) / 8, BB * NH), blk, 0, stream>>>(buf2, buf3, buf4, buf0);

    // x1 = attnV @ Wo + bo + queries
    gemm64<<<gq, blk, 0, stream>>>(buf0, Wo, bo, queries, buf5, Mq, EE, EE, 0);

    // qc = ln2(x1) + query_pos
    ln_kernel<<<Mq, blk, 0, stream>>>(buf5, ln2_s, ln2_b, query_pos, nullptr, buf1);

    // off, att logits
    gemm64<<<dim3(256 / 64, (Mq + 63) / 64), blk, 0, stream>>>(
        buf1, Woff, boff, nullptr, buf0, Mq, EE, 256, 0);
    gemm64<<<dim3(128 / 64, (Mq + 63) / 64), blk, 0, stream>>>(
        buf1, Watt, batt, nullptr, buf2, Mq, EE, 128, 0);

    // aw softmax + loc
    locaw_kernel<<<Mq, blk, 0, stream>>>(buf2, buf0, refp, aw_out, loc_out);

    // bilinear sampling -> samp (buf2)
    sample_kernel<<<Mq, blk, 0, stream>>>(bufVal, aw_out, loc_out, shapes, starts, buf2, NV);

    // cross = samp @ Wop + bop
    gemm64<<<gq, blk, 0, stream>>>(buf2, Wop, bop, nullptr, buf3, Mq, EE, EE, 0);

    // g = sigmoid(x1 @ Wg_top + cross @ Wg_bot + bg)
    gemm64<<<dim3(512 / 64, (Mq + 63) / 64), blk, 0, stream>>>(
        buf5, Wg, bg, nullptr, bufG, Mq, EE, 512, 0);
    gemm64<<<dim3(512 / 64, (Mq + 63) / 64), blk, 0, stream>>>(
        buf3, Wg + 256 * 512, nullptr, bufG, bufG, Mq, EE, 512, 2);

    // x2 = g1*x1 + g2*cross
    gate_kernel<<<(Mq * EE + 255) / 256, blk, 0, stream>>>(bufG, buf5, buf3, buf4, Mq * EE);

    // z = ln3(x2)
    ln_kernel<<<Mq, blk, 0, stream>>>(buf4, ln3_s, ln3_b, nullptr, buf0, nullptr);

    // ffn hidden = relu(z @ W1 + b1)
    gemm64<<<dim3(FFN_H / 64, (Mq + 63) / 64), blk, 0, stream>>>(
        buf0, W1, b1, nullptr, bufG, Mq, EE, FFN_H, 1);

    // out0 = hidden @ W2 + b2 + x2
    gemm64<<<dim3(EE / 64, (Mq + 63) / 64), blk, 0, stream>>>(
        bufG, W2, b2, buf4, out0, Mq, FFN_H, EE, 0);
}

// Round 2
// 527.281 us; speedup vs baseline: 3.3573x; 3.3573x over previous
//
#include <hip/hip_runtime.h>
#include <hip/hip_bf16.h>
#include <math.h>

#define BB 8
#define LQ 900
#define EE 256
#define NH 8
#define HD 32
#define NL 4
#define NP 4
#define FFN_H 1024

typedef __bf16 bf16x8 __attribute__((ext_vector_type(8)));
typedef float f32x4 __attribute__((ext_vector_type(4)));
typedef unsigned short u16x8 __attribute__((ext_vector_type(8)));
typedef unsigned short ushort_t;

__device__ __forceinline__ unsigned short f2b(float f) {
    union { float f; unsigned int u; } v; v.f = f;
    unsigned int u = v.u;
    unsigned int r = (u + 0x7fffu + ((u >> 16) & 1u)) >> 16;
    return (unsigned short)r;
}
__device__ __forceinline__ float b2f(unsigned short h) {
    union { unsigned int u; float f; } v; v.u = ((unsigned int)h) << 16; return v.f;
}

// ---------------------------------------------------------------------------
// Batched weight transpose + cast: dst[n][k] = bf16(src[k][n])
// ---------------------------------------------------------------------------
struct TDesc { const float* src; unsigned short* dst; int K, N, tile0; };
struct TPack { TDesc d[12]; };

__global__ __launch_bounds__(256) void trans_kernel(TPack p) {
    int bi = blockIdx.x;
    int di = 0;
#pragma unroll
    for (int i = 1; i < 12; ++i) if (bi >= p.d[i].tile0) di = i;
    TDesc d = p.d[di];
    int t = bi - d.tile0;
    int tn = (d.N + 31) >> 5;
    int tk = t / tn, tc = t % tn;
    __shared__ float tile[32][33];
    int tx = threadIdx.x & 31, ty = threadIdx.x >> 5;
#pragma unroll
    for (int i = 0; i < 4; ++i) {
        int kk = tk * 32 + ty + i * 8, nn = tc * 32 + tx;
        tile[ty + i * 8][tx] = d.src[(size_t)kk * d.N + nn];
    }
    __syncthreads();
#pragma unroll
    for (int i = 0; i < 4; ++i) {
        int nn = tc * 32 + ty + i * 8, kk = tk * 32 + tx;
        d.dst[(size_t)nn * d.K + kk] = f2b(tile[tx][ty + i * 8]);
    }
}

__global__ void bcat_kernel(const float* __restrict__ a, const float* __restrict__ b,
                            float* __restrict__ o) {
    int t = blockIdx.x * 256 + threadIdx.x;
    if (t < 256) o[t] = a[t];
    else if (t < 512) o[t] = b[t - 256];
}

__global__ __launch_bounds__(256) void cast_kernel(const float* __restrict__ in,
                                                   unsigned short* __restrict__ out, long n) {
    long i = ((long)blockIdx.x * 256 + threadIdx.x) * 8;
    long stride = (long)gridDim.x * 256 * 8;
    for (; i < n; i += stride) {
        float4 a = *(const float4*)(in + i);
        float4 b = *(const float4*)(in + i + 4);
        u16x8 o;
        o[0] = f2b(a.x); o[1] = f2b(a.y); o[2] = f2b(a.z); o[3] = f2b(a.w);
        o[4] = f2b(b.x); o[5] = f2b(b.y); o[6] = f2b(b.z); o[7] = f2b(b.w);
        *(u16x8*)(out + i) = o;
    }
}

// ---------------------------------------------------------------------------
// LayerNorm (E=256), writes bf16 outputs: outx = ln(in), outxa = ln(in)+add
// ---------------------------------------------------------------------------
__global__ __launch_bounds__(256) void ln_bf(
    const float* __restrict__ in, const float* __restrict__ s,
    const float* __restrict__ b, const float* __restrict__ add,
    unsigned short* __restrict__ outx, unsigned short* __restrict__ outxa)
{
    const int row = blockIdx.x;
    const int t = threadIdx.x;
    const int w = t >> 6;
    const int lane = t & 63;
    __shared__ float red[4];

    float v = in[(size_t)row * EE + t];
    float sum = v;
#pragma unroll
    for (int o = 32; o; o >>= 1) sum += __shfl_xor(sum, o, 64);
    if (lane == 0) red[w] = sum;
    __syncthreads();
    float mean = (red[0] + red[1] + red[2] + red[3]) * (1.0f / 256.0f);
    __syncthreads();

    float d = v - mean;
    float sq = d * d;
#pragma unroll
    for (int o = 32; o; o >>= 1) sq += __shfl_xor(sq, o, 64);
    if (lane == 0) red[w] = sq;
    __syncthreads();
    float var = (red[0] + red[1] + red[2] + red[3]) * (1.0f / 256.0f);

    float y = d * rsqrtf(var + 1e-5f) * s[t] + b[t];
    if (outx)  outx[(size_t)row * EE + t] = f2b(y);
    if (outxa) outxa[(size_t)row * EE + t] = f2b(y + add[(size_t)row * EE + t]);
}

// ---------------------------------------------------------------------------
// bf16 MFMA GEMM: C[M,N] = act(A[M,K] @ Wt[N,K]^T + bias + resid)
// 128x128 tile, BK=64, 256 thr (4 waves 2x2), 16x16x32 MFMA, XOR-swizzled LDS.
// ---------------------------------------------------------------------------
__global__ __launch_bounds__(256) void gemm_bf(
    const unsigned short* __restrict__ A, const unsigned short* __restrict__ Wt,
    const float* __restrict__ bias, const float* __restrict__ resid,
    float* __restrict__ outF, unsigned short* __restrict__ outB,
    int M, int K, int N, int act)
{
    __shared__ __align__(16) unsigned short As[128 * 64];
    __shared__ __align__(16) unsigned short Bs[128 * 64];
    const int tid = threadIdx.x;
    const int l = tid & 63, w = tid >> 6;
    const int m0 = blockIdx.y * 128, n0 = blockIdx.x * 128;

    f32x4 acc[4][4];
#pragma unroll
    for (int i = 0; i < 4; ++i)
#pragma unroll
        for (int j = 0; j < 4; ++j) acc[i][j] = (f32x4){0.f, 0.f, 0.f, 0.f};

    const int arow = tid >> 1;            // 0..127
    const int abyte = (tid & 1) * 64;     // byte half of 128B row
    const int swz = (arow & 7) << 4;

    int rg = m0 + arow; rg = rg < M ? rg : M - 1;
    const unsigned short* ga = A + (size_t)rg * K + abyte / 2;
    const unsigned short* gb = Wt + (size_t)(n0 + arow) * K + abyte / 2;

    const int wm = (w >> 1) * 64, wn = (w & 1) * 64;

    for (int k0 = 0; k0 < K; k0 += 64) {
        __syncthreads();
#pragma unroll
        for (int c = 0; c < 4; ++c) {
            u16x8 va = *(const u16x8*)(ga + k0 + c * 8);
            *(u16x8*)((char*)As + arow * 128 + ((abyte + c * 16) ^ swz)) = va;
            u16x8 vb = *(const u16x8*)(gb + k0 + c * 8);
            *(u16x8*)((char*)Bs + arow * 128 + ((abyte + c * 16) ^ swz)) = vb;
        }
        __syncthreads();
#pragma unroll
        for (int s = 0; s < 2; ++s) {
            bf16x8 af[4], bfr[4];
#pragma unroll
            for (int i = 0; i < 4; ++i) {
                int r = wm + i * 16 + (l & 15);
                af[i] = *(const bf16x8*)((const char*)As + r * 128 +
                        ((s * 64 + ((l >> 4) * 16)) ^ ((r & 7) << 4)));
                int rb = wn + i * 16 + (l & 15);
                bfr[i] = *(const bf16x8*)((const char*)Bs + rb * 128 +
                        ((s * 64 + ((l >> 4) * 16)) ^ ((rb & 7) << 4)));
            }
#pragma unroll
            for (int i = 0; i < 4; ++i)
#pragma unroll
                for (int j = 0; j < 4; ++j)
                    acc[i][j] = __builtin_amdgcn_mfma_f32_16x16x32_bf16(af[i], bfr[j], acc[i][j], 0, 0, 0);
        }
    }

#pragma unroll
    for (int i = 0; i < 4; ++i) {
#pragma unroll
        for (int r = 0; r < 4; ++r) {
            int gm = m0 + wm + i * 16 + (l >> 4) * 4 + r;
            if (gm >= M) continue;
#pragma unroll
            for (int j = 0; j < 4; ++j) {
                int gn = n0 + wn + j * 16 + (l & 15);
                float v = acc[i][j][r];
                if (bias)  v += bias[gn];
                if (resid) v += resid[(size_t)gm * N + gn];
                if (act == 1)      v = fmaxf(v, 0.f);
                else if (act == 2) v = 1.0f / (1.0f + __expf(-v));
                if (outF) outF[(size_t)gm * N + gn] = v;
                if (outB) outB[(size_t)gm * N + gn] = f2b(v);
            }
        }
    }
}

// ---------------------------------------------------------------------------
// Fused MFMA flash self-attention.
// grid (15, B*NH), block 256 (4 waves); wave w owns 16 q-rows.
// QK: [7200][512] bf16 (Q cols 0-255, K cols 256-511); Vb: [7200][256] bf16.
// ---------------------------------------------------------------------------
__global__ __launch_bounds__(256) void attn_mfma(
    const unsigned short* __restrict__ QK, const unsigned short* __restrict__ Vb,
    unsigned short* __restrict__ outB)
{
    const int qt = blockIdx.x;
    const int bh = blockIdx.y;
    const int b = bh >> 3, h = bh & 7;
    const int tid = threadIdx.x;
    const int w = tid >> 6, l = tid & 63;

    __shared__ __align__(16) unsigned short Ks[64 * 32];   // [key][d], 64B rows, swz (key&3)<<4
    __shared__ __align__(16) unsigned short VT[32 * 64];   // [d][key], 128B rows, swz (d&7)<<4
    __shared__ __align__(16) unsigned short Ps[4][64 * 20];// per-wave P^T [key][q], 40B rows

    const int qrow_w = qt * 64 + w * 16;
    int qr = qrow_w + (l & 15); qr = qr < LQ ? qr : LQ - 1;
    bf16x8 qf = *(const bf16x8*)(QK + ((size_t)(b * LQ + qr)) * 512 + h * 32 + (l >> 4) * 8);

    f32x4 acc0 = {0.f, 0.f, 0.f, 0.f}, acc1 = {0.f, 0.f, 0.f, 0.f};
    float m_run = -1e30f, l_run = 0.f;
    const float scale = 0.17677669529663689f;
    const f32x4 z4 = {0.f, 0.f, 0.f, 0.f};

    for (int kt = 0; kt < 15; ++kt) {
        __syncthreads();
        {
            int key = tid >> 2;
            int dg = (tid & 3) * 8;
            int krow = kt * 64 + key; krow = krow < LQ ? krow : LQ - 1;
            size_t base = (size_t)(b * LQ + krow);
            u16x8 kv = *(const u16x8*)(QK + base * 512 + 256 + h * 32 + dg);
            *(u16x8*)((char*)Ks + key * 64 + ((dg * 2) ^ ((key & 3) << 4))) = kv;
            u16x8 vv = *(const u16x8*)(Vb + base * 256 + h * 32 + dg);
#pragma unroll
            for (int e = 0; e < 8; ++e) {
                int d = dg + e;
                *(unsigned short*)((char*)VT + d * 128 + ((key * 2) ^ ((d & 7) << 4))) = vv[e];
            }
        }
        __syncthreads();

        // S^T = K * Q^T
        float p[4][4];
        float tmax = -1e30f;
#pragma unroll
        for (int m = 0; m < 4; ++m) {
            int kr = m * 16 + (l & 15);
            bf16x8 kf = *(const bf16x8*)((const char*)Ks + kr * 64 +
                        (((l >> 4) * 16) ^ ((kr & 3) << 4)));
            f32x4 sf = __builtin_amdgcn_mfma_f32_16x16x32_bf16(kf, qf, z4, 0, 0, 0);
#pragma unroll
            for (int r = 0; r < 4; ++r) {
                int key = kt * 64 + m * 16 + (l >> 4) * 4 + r;
                float sv = (key < LQ) ? sf[r] * scale : -1e30f;
                p[m][r] = sv;
                tmax = fmaxf(tmax, sv);
            }
        }
        tmax = fmaxf(tmax, __shfl_xor(tmax, 16, 64));
        tmax = fmaxf(tmax, __shfl_xor(tmax, 32, 64));
        float newm = fmaxf(m_run, tmax);
        float corr = __expf(m_run - newm);
        m_run = newm;
        float tsum = 0.f;
#pragma unroll
        for (int m = 0; m < 4; ++m)
#pragma unroll
            for (int r = 0; r < 4; ++r) {
                float e = __expf(p[m][r] - newm);
                p[m][r] = e;
                tsum += e;
            }
        tsum += __shfl_xor(tsum, 16, 64);
        tsum += __shfl_xor(tsum, 32, 64);
        l_run = l_run * corr + tsum;
        acc0 *= corr;
        acc1 *= corr;

        unsigned short* pw = &Ps[w][0];
#pragma unroll
        for (int m = 0; m < 4; ++m)
#pragma unroll
            for (int r = 0; r < 4; ++r) {
                int key = m * 16 + (l >> 4) * 4 + r;
                pw[key * 20 + (l & 15)] = f2b(p[m][r]);
            }

        // O^T += V^T * P
#pragma unroll
        for (int s = 0; s < 2; ++s) {
            union { unsigned short u[8]; bf16x8 v; } pb;
#pragma unroll
            for (int j = 0; j < 8; ++j)
                pb.u[j] = pw[(s * 32 + (l >> 4) * 8 + j) * 20 + (l & 15)];
#pragma unroll
            for (int m2 = 0; m2 < 2; ++m2) {
                int d = m2 * 16 + (l & 15);
                bf16x8 vf = *(const bf16x8*)((const char*)VT + d * 128 +
                            ((s * 64 + (l >> 4) * 16) ^ ((d & 7) << 4)));
                if (m2 == 0) acc0 = __builtin_amdgcn_mfma_f32_16x16x32_bf16(vf, pb.v, acc0, 0, 0, 0);
                else         acc1 = __builtin_amdgcn_mfma_f32_16x16x32_bf16(vf, pb.v, acc1, 0, 0, 0);
            }
        }
    }

    float inv = 1.0f / l_run;
    int q = qrow_w + (l & 15);
    if (q < LQ) {
        size_t obase = ((size_t)(b * LQ + q)) * 256 + h * 32;
#pragma unroll
        for (int r = 0; r < 4; ++r) {
            int d0 = (l >> 4) * 4 + r;
            outB[obase + d0]      = f2b(acc0[r] * inv);
            outB[obase + 16 + d0] = f2b(acc1[r] * inv);
        }
    }
}

// ---------------------------------------------------------------------------
// Sampling-weight softmax + sampling locations (fp32 outputs to d_out).
// ---------------------------------------------------------------------------
__global__ __launch_bounds__(256) void locaw_kernel(
    const float* __restrict__ att, const float* __restrict__ off,
    const float* __restrict__ refp, float* __restrict__ aw_out,
    float* __restrict__ loc_out)
{
    const int row = blockIdx.x;
    const int t = threadIdx.x;
    __shared__ float a_l[128];
    if (t < 128) a_l[t] = att[(size_t)row * 128 + t];
    __syncthreads();
    if (t < 128) {
        int h = t >> 4;
        float mx = -1e30f;
#pragma unroll
        for (int i = 0; i < 16; ++i) mx = fmaxf(mx, a_l[h * 16 + i]);
        float sum = 0.f;
#pragma unroll
        for (int i = 0; i < 16; ++i) sum += __expf(a_l[h * 16 + i] - mx);
        aw_out[(size_t)row * 128 + t] = __expf(a_l[t] - mx) / sum;
    }
    float o = off[(size_t)row * 256 + t];
    int c = t & 1;
    int lv = (t >> 3) & 3;
    float rc = refp[((size_t)row * 4 + lv) * 4 + c];
    float rs = refp[((size_t)row * 4 + lv) * 4 + 2 + c];
    loc_out[(size_t)row * 256 + t] = rc + o * 0.125f * rs;
}

// ---------------------------------------------------------------------------
// Deformable bilinear sampling from bf16 val -> bf16 samp.
// ---------------------------------------------------------------------------
__global__ __launch_bounds__(256) void sample_kernel(
    const unsigned short* __restrict__ val, const float* __restrict__ aw,
    const float* __restrict__ loc, const int* __restrict__ shapes,
    const int* __restrict__ starts, unsigned short* __restrict__ samp, int NV)
{
    const int row = blockIdx.x;
    const int b = row / LQ;
    const int t = threadIdx.x;
    const int h = t >> 5, d = t & 31;

    __shared__ float l_loc[256];
    __shared__ float l_aw[128];
    __shared__ int l_sh[NL * 2];
    __shared__ int l_st[NL];

    l_loc[t] = loc[(size_t)row * 256 + t];
    if (t < 128) l_aw[t] = aw[(size_t)row * 128 + t];
    if (t < NL * 2) l_sh[t] = shapes[t];
    if (t < NL) l_st[t] = starts[t];
    __syncthreads();

    float acc = 0.f;
    const unsigned short* vb = val + (size_t)b * NV * EE + h * HD + d;

#pragma unroll
    for (int lv = 0; lv < NL; ++lv) {
        const int Hh = l_sh[lv * 2], Ww = l_sh[lv * 2 + 1];
        const int s0 = l_st[lv];
#pragma unroll
        for (int p = 0; p < NP; ++p) {
            const int base = ((h * NL + lv) * NP + p) * 2;
            float lx = l_loc[base], ly = l_loc[base + 1];
            float wgt0 = l_aw[h * 16 + lv * NP + p];
            float px = lx * (float)Ww - 0.5f;
            float py = ly * (float)Hh - 0.5f;
            float x0f = floorf(px), y0f = floorf(py);
            float wx = px - x0f, wy = py - y0f;
            int x0 = (int)x0f, y0 = (int)y0f;
#pragma unroll
            for (int dy = 0; dy < 2; ++dy) {
                int yi = y0 + dy;
                bool vy = (yi >= 0) && (yi < Hh);
                int yc = min(max(yi, 0), Hh - 1);
                float wyv = dy ? wy : 1.f - wy;
#pragma unroll
                for (int dx = 0; dx < 2; ++dx) {
                    int xi = x0 + dx;
                    bool vv = vy && (xi >= 0) && (xi < Ww);
                    int xc = min(max(xi, 0), Ww - 1);
                    float wgt = wgt0 * wyv * (dx ? wx : 1.f - wx);
                    float gv = b2f(vb[(size_t)(s0 + yc * Ww + xc) * EE]);
                    acc += vv ? wgt * gv : 0.f;
                }
            }
        }
    }
    samp[(size_t)row * EE + t] = f2b(acc);
}

// ---------------------------------------------------------------------------
// Gated fusion + ln3: x2 = g1*x1 + g2*cross; z_b = bf16(ln3(x2))
// ---------------------------------------------------------------------------
__global__ __launch_bounds__(256) void gate_ln3(
    const float* __restrict__ g, const float* __restrict__ x1,
    const float* __restrict__ cross, const float* __restrict__ s,
    const float* __restrict__ bln, float* __restrict__ x2out,
    unsigned short* __restrict__ zb)
{
    const int row = blockIdx.x;
    const int t = threadIdx.x;
    const int w = t >> 6;
    const int lane = t & 63;
    __shared__ float red[4];

    float g1 = g[(size_t)row * 512 + t];
    float g2 = g[(size_t)row * 512 + 256 + t];
    float v = g1 * x1[(size_t)row * EE + t] + g2 * cross[(size_t)row * EE + t];
    x2out[(size_t)row * EE + t] = v;

    float sum = v;
#pragma unroll
    for (int o = 32; o; o >>= 1) sum += __shfl_xor(sum, o, 64);
    if (lane == 0) red[w] = sum;
    __syncthreads();
    float mean = (red[0] + red[1] + red[2] + red[3]) * (1.0f / 256.0f);
    __syncthreads();

    float d = v - mean;
    float sq = d * d;
#pragma unroll
    for (int o = 32; o; o >>= 1) sq += __shfl_xor(sq, o, 64);
    if (lane == 0) red[w] = sq;
    __syncthreads();
    float var = (red[0] + red[1] + red[2] + red[3]) * (1.0f / 256.0f);

    float y = d * rsqrtf(var + 1e-5f) * s[t] + bln[t];
    zb[(size_t)row * EE + t] = f2b(y);
}

// ---------------------------------------------------------------------------
extern "C" void kernel_launch(void* const* d_in, const int* in_sizes, int n_in,
                              void* d_out, int out_size, void* d_ws, size_t ws_size,
                              hipStream_t stream)
{
    const float* queries   = (const float*)d_in[0];
    const float* memory    = (const float*)d_in[1];
    const float* query_pos = (const float*)d_in[2];
    const float* refp      = (const float*)d_in[3];
    const int*   shapes    = (const int*)d_in[4];
    const int*   starts    = (const int*)d_in[5];
    const float* Wq  = (const float*)d_in[6],  *bq  = (const float*)d_in[7];
    const float* Wk  = (const float*)d_in[8],  *bk  = (const float*)d_in[9];
    const float* Wv  = (const float*)d_in[10], *bv  = (const float*)d_in[11];
    const float* Wo  = (const float*)d_in[12], *bo  = (const float*)d_in[13];
    const float* Wvd = (const float*)d_in[14], *bvd = (const float*)d_in[15];
    const float* Woff= (const float*)d_in[16], *boff= (const float*)d_in[17];
    const float* Watt= (const float*)d_in[18], *batt= (const float*)d_in[19];
    const float* Wop = (const float*)d_in[20], *bop = (const float*)d_in[21];
    const float* Wg  = (const float*)d_in[22], *bg  = (const float*)d_in[23];
    const float* W1  = (const float*)d_in[24], *b1  = (const float*)d_in[25];
    const float* W2  = (const float*)d_in[26], *b2  = (const float*)d_in[27];
    const float* ln1_s = (const float*)d_in[28], *ln1_b = (const float*)d_in[29];
    const float* ln2_s = (const float*)d_in[30], *ln2_b = (const float*)d_in[31];
    const float* ln3_s = (const float*)d_in[32], *ln3_b = (const float*)d_in[33];

    const int NV = in_sizes[1] / (BB * EE);   // 13294
    const int Mq = BB * LQ;                   // 7200
    const long memN = (long)BB * NV * EE;     // 27,226,112

    // ---- workspace layout (bytes) ----
    char* W8 = (char*)d_ws;
    size_t off = 0;
    auto alloc = [&](size_t bytes) { char* p = W8 + off; off += (bytes + 255) & ~(size_t)255; return p; };

    unsigned short* mem_b   = (unsigned short*)alloc((size_t)memN * 2);   // later: gbuf/x2/zb/hidden
    unsigned short* val_b   = (unsigned short*)alloc((size_t)memN * 2);
    unsigned short* WtQK    = (unsigned short*)alloc(512 * 256 * 2);
    unsigned short* WtV     = (unsigned short*)alloc(256 * 256 * 2);
    unsigned short* WtO     = (unsigned short*)alloc(256 * 256 * 2);
    unsigned short* WtVD    = (unsigned short*)alloc(256 * 256 * 2);
    unsigned short* WtOFF   = (unsigned short*)alloc(256 * 256 * 2);
    unsigned short* WtATT   = (unsigned short*)alloc(128 * 256 * 2);
    unsigned short* WtOP    = (unsigned short*)alloc(256 * 256 * 2);
    unsigned short* WtG1    = (unsigned short*)alloc(512 * 256 * 2);
    unsigned short* WtG2    = (unsigned short*)alloc(512 * 256 * 2);
    unsigned short* Wt1     = (unsigned short*)alloc(1024 * 256 * 2);
    unsigned short* Wt2     = (unsigned short*)alloc(256 * 1024 * 2);
    float*          bqk     = (float*)alloc(512 * 4);
    char* regA              = alloc((size_t)Mq * 256 * 4);   // x_b|qk_b -> off_f
    char* regQKB            = alloc((size_t)Mq * 512 * 2);   // qkb -> attl -> cross
    unsigned short* vb_buf  = (unsigned short*)alloc((size_t)Mq * 256 * 2);   // vb -> cross_b
    unsigned short* av_buf  = (unsigned short*)alloc((size_t)Mq * 256 * 2);   // attnV_b -> samp_b
    float*          x1      = (float*)alloc((size_t)Mq * 256 * 4);
    unsigned short* x1_b    = (unsigned short*)alloc((size_t)Mq * 256 * 2);
    unsigned short* qc_b    = (unsigned short*)alloc((size_t)Mq * 256 * 2);

    // aliases
    unsigned short* x_b  = (unsigned short*)regA;
    unsigned short* qk_b = (unsigned short*)(regA + (size_t)Mq * 256 * 2);
    float* off_f = (float*)regA;
    unsigned short* qkb  = (unsigned short*)regQKB;
    float* attl  = (float*)regQKB;
    float* cross = (float*)regQKB;
    unsigned short* cross_b = vb_buf;
    unsigned short* samp_b  = av_buf;
    // reuse mem_b region after val gemm:
    float* gbuf = (float*)mem_b;                                    // 7200*512 f32
    float* x2   = (float*)((char*)mem_b + (size_t)Mq * 512 * 4);    // 7200*256 f32
    unsigned short* z_b = (unsigned short*)((char*)x2 + (size_t)Mq * 256 * 4);
    unsigned short* hidden_b = (unsigned short*)((char*)z_b + (size_t)Mq * 256 * 2);

    float* out0    = (float*)d_out;
    float* aw_out  = out0 + (size_t)Mq * 256;
    float* loc_out = aw_out + (size_t)Mq * 128;

    dim3 blk(256);

    // 1. weight transpose+cast (batched)
    TPack tp;
    tp.d[0]  = { Wq,             WtQK,             256, 256,    0 };
    tp.d[1]  = { Wk,             WtQK + 256 * 256, 256, 256,   64 };
    tp.d[2]  = { Wv,             WtV,              256, 256,  128 };
    tp.d[3]  = { Wo,             WtO,              256, 256,  192 };
    tp.d[4]  = { Wvd,            WtVD,             256, 256,  256 };
    tp.d[5]  = { Woff,           WtOFF,            256, 256,  320 };
    tp.d[6]  = { Watt,           WtATT,            256, 128,  384 };
    tp.d[7]  = { Wop,            WtOP,             256, 256,  416 };
    tp.d[8]  = { Wg,             WtG1,             256, 512,  480 };
    tp.d[9]  = { Wg + 256 * 512, WtG2,             256, 512,  608 };
    tp.d[10] = { W1,             Wt1,              256, 1024, 736 };
    tp.d[11] = { W2,             Wt2,             1024, 256,  992 };
    trans_kernel<<<1248, blk, 0, stream>>>(tp);

    // 2. bias concat, 3. cast memory
    bcat_kernel<<<2, blk, 0, stream>>>(bq, bk, bqk);
    cast_kernel<<<2048, blk, 0, stream>>>(memory, mem_b, memN);

    // 4. ln1
    ln_bf<<<Mq, blk, 0, stream>>>(queries, ln1_s, ln1_b, query_pos, x_b, qk_b);

    // 5-7. QK, V, val projections
    gemm_bf<<<dim3(4, 57), blk, 0, stream>>>(qk_b, WtQK, bqk, nullptr, nullptr, qkb, Mq, 256, 512, 0);
    gemm_bf<<<dim3(2, 57), blk, 0, stream>>>(x_b, WtV, bv, nullptr, nullptr, vb_buf, Mq, 256, 256, 0);
    gemm_bf<<<dim3(2, 831), blk, 0, stream>>>(mem_b, WtVD, bvd, nullptr, nullptr, val_b, BB * NV, 256, 256, 0);

    // 8. self-attention
    attn_mfma<<<dim3(15, BB * NH), blk, 0, stream>>>(qkb, vb_buf, av_buf);

    // 9. x1 = attnV @ Wo + bo + queries
    gemm_bf<<<dim3(2, 57), blk, 0, stream>>>(av_buf, WtO, bo, queries, x1, x1_b, Mq, 256, 256, 0);

    // 10. qc = ln2(x1) + pos
    ln_bf<<<Mq, blk, 0, stream>>>(x1, ln2_s, ln2_b, query_pos, nullptr, qc_b);

    // 11-12. off / att logits
    gemm_bf<<<dim3(2, 57), blk, 0, stream>>>(qc_b, WtOFF, boff, nullptr, off_f, nullptr, Mq, 256, 256, 0);
    gemm_bf<<<dim3(1, 57), blk, 0, stream>>>(qc_b, WtATT, batt, nullptr, attl, nullptr, Mq, 256, 128, 0);

    // 13. aw softmax + loc
    locaw_kernel<<<Mq, blk, 0, stream>>>(attl, off_f, refp, aw_out, loc_out);

    // 14. bilinear sampling
    sample_kernel<<<Mq, blk, 0, stream>>>(val_b, aw_out, loc_out, shapes, starts, samp_b, NV);

    // 15. cross = samp @ Wop + bop
    gemm_bf<<<dim3(2, 57), blk, 0, stream>>>(samp_b, WtOP, bop, nullptr, cross, cross_b, Mq, 256, 256, 0);

    // 16-17. gate
    gemm_bf<<<dim3(4, 57), blk, 0, stream>>>(x1_b, WtG1, bg, nullptr, gbuf, nullptr, Mq, 256, 512, 0);
    gemm_bf<<<dim3(4, 57), blk, 0, stream>>>(cross_b, WtG2, nullptr, gbuf, gbuf, nullptr, Mq, 256, 512, 2);

    // 18. x2 + ln3
    gate_ln3<<<Mq, blk, 0, stream>>>(gbuf, x1, cross, ln3_s, ln3_b, x2, z_b);

    // 19-20. FFN
    gemm_bf<<<dim3(8, 57), blk, 0, stream>>>(z_b, Wt1, b1, nullptr, nullptr, hidden_b, Mq, 256, 1024, 1);
    gemm_bf<<<dim3(2, 57), blk, 0, stream>>>(hidden_b, Wt2, b2, x2, out0, nullptr, Mq, 1024, 256, 0);
}

// Round 3
// 333.673 us; speedup vs baseline: 5.3053x; 1.5802x over previous
//
#include <hip/hip_runtime.h>
#include <hip/hip_bf16.h>
#include <math.h>

#define BB 8
#define LQ 900
#define EE 256
#define NH 8
#define HD 32
#define NL 4
#define NP 4
#define FFN_H 1024

typedef __bf16 bf16x8 __attribute__((ext_vector_type(8)));
typedef float f32x4 __attribute__((ext_vector_type(4)));
typedef unsigned short u16x8 __attribute__((ext_vector_type(8)));

__device__ __forceinline__ unsigned short f2b(float f) {
    union { float f; unsigned int u; } v; v.f = f;
    unsigned int u = v.u;
    unsigned int r = (u + 0x7fffu + ((u >> 16) & 1u)) >> 16;
    return (unsigned short)r;
}
__device__ __forceinline__ float b2f(unsigned short h) {
    union { unsigned int u; float f; } v; v.u = ((unsigned int)h) << 16; return v.f;
}

typedef __attribute__((address_space(3))) unsigned int* lds_ptr_t;
typedef const __attribute__((address_space(1))) unsigned int* gbl_ptr_t;
#define GLOAD16(g, l) __builtin_amdgcn_global_load_lds((gbl_ptr_t)(g), (lds_ptr_t)(l), 16, 0, 0)
#define VMCNT(n) asm volatile("s_waitcnt vmcnt(" #n ")" ::: "memory")

// ---------------------------------------------------------------------------
// Batched weight transpose + cast: dst[n][k] = bf16(src[k][n])
// ---------------------------------------------------------------------------
struct TDesc { const float* src; unsigned short* dst; int K, N, tile0; };
struct TPack { TDesc d[11]; };

__global__ __launch_bounds__(256) void trans_kernel(TPack p) {
    int bi = blockIdx.x;
    int di = 0;
#pragma unroll
    for (int i = 1; i < 11; ++i) if (bi >= p.d[i].tile0) di = i;
    TDesc d = p.d[di];
    int t = bi - d.tile0;
    int tn = (d.N + 31) >> 5;
    int tk = t / tn, tc = t % tn;
    __shared__ float tile[32][33];
    int tx = threadIdx.x & 31, ty = threadIdx.x >> 5;
#pragma unroll
    for (int i = 0; i < 4; ++i) {
        int kk = tk * 32 + ty + i * 8, nn = tc * 32 + tx;
        tile[ty + i * 8][tx] = d.src[(size_t)kk * d.N + nn];
    }
    __syncthreads();
#pragma unroll
    for (int i = 0; i < 4; ++i) {
        int nn = tc * 32 + ty + i * 8, kk = tk * 32 + tx;
        d.dst[(size_t)nn * d.K + kk] = f2b(tile[tx][ty + i * 8]);
    }
}

__global__ void bcat_kernel(const float* __restrict__ a, const float* __restrict__ b,
                            float* __restrict__ o) {
    int t = blockIdx.x * 256 + threadIdx.x;
    if (t < 256) o[t] = a[t];
    else if (t < 512) o[t] = b[t - 256];
}

__global__ __launch_bounds__(256) void cast_kernel(const float* __restrict__ in,
                                                   unsigned short* __restrict__ out, long n) {
    long i = ((long)blockIdx.x * 256 + threadIdx.x) * 8;
    long stride = (long)gridDim.x * 256 * 8;
    for (; i < n; i += stride) {
        float4 a = *(const float4*)(in + i);
        float4 b = *(const float4*)(in + i + 4);
        u16x8 o;
        o[0] = f2b(a.x); o[1] = f2b(a.y); o[2] = f2b(a.z); o[3] = f2b(a.w);
        o[4] = f2b(b.x); o[5] = f2b(b.y); o[6] = f2b(b.z); o[7] = f2b(b.w);
        *(u16x8*)(out + i) = o;
    }
}

// ---------------------------------------------------------------------------
// LayerNorm (E=256): outx = bf16(ln(in)), outxa = bf16(ln(in)+add)
// ---------------------------------------------------------------------------
__global__ __launch_bounds__(256) void ln_bf(
    const float* __restrict__ in, const float* __restrict__ s,
    const float* __restrict__ b, const float* __restrict__ add,
    unsigned short* __restrict__ outx, unsigned short* __restrict__ outxa)
{
    const int row = blockIdx.x;
    const int t = threadIdx.x;
    const int w = t >> 6;
    const int lane = t & 63;
    __shared__ float red[4];

    float v = in[(size_t)row * EE + t];
    float sum = v;
#pragma unroll
    for (int o = 32; o; o >>= 1) sum += __shfl_xor(sum, o, 64);
    if (lane == 0) red[w] = sum;
    __syncthreads();
    float mean = (red[0] + red[1] + red[2] + red[3]) * (1.0f / 256.0f);
    __syncthreads();

    float d = v - mean;
    float sq = d * d;
#pragma unroll
    for (int o = 32; o; o >>= 1) sq += __shfl_xor(sq, o, 64);
    if (lane == 0) red[w] = sq;
    __syncthreads();
    float var = (red[0] + red[1] + red[2] + red[3]) * (1.0f / 256.0f);

    float y = d * rsqrtf(var + 1e-5f) * s[t] + b[t];
    if (outx)  outx[(size_t)row * EE + t] = f2b(y);
    if (outxa) outxa[(size_t)row * EE + t] = f2b(y + add[(size_t)row * EE + t]);
}

// ---------------------------------------------------------------------------
// Batched persistent pipelined bf16 MFMA GEMM.
// Tile BM=64 x BN=128, BK=32, 256 thr (4 waves 2x2, each wave 32x64).
// Double-buffered LDS (2 x 12KB), global_load_lds(16B) with pre-swizzled
// per-lane source + linear LDS dest; counted vmcnt(3); raw s_barrier.
// C = act(A[M,K] @ Bt[N,K]^T + bias + resid)
// ---------------------------------------------------------------------------
struct GD {
    const unsigned short* A;
    const unsigned short* Bt;
    const float* bias;
    const float* resid;
    float* outF;
    unsigned short* outB;
    int M, K, N, ntN, tile0, ldOutB, outBoff, act;
};
struct GB { GD d[3]; int nd, tot; };

__global__ __launch_bounds__(256, 4) void gemm_pipe(GB g) {
    __shared__ __align__(16) unsigned short ldsbuf[2][(64 + 128) * 32];
    const int tid = threadIdx.x;
    const int l = tid & 63, w = tid >> 6;
    const int wr = w >> 1, wc = w & 1;
    const int lrow = l >> 2;                              // row within 16-row issue
    const int schunk = (((l & 3) ^ ((l >> 2) & 3)) << 4); // source chunk byte offset
    const int rch = (((l >> 4) ^ (l & 3)) << 4);          // read chunk byte offset

    int t = blockIdx.x;
    if (t >= g.tot) return;
    int d = 0;
    while (d + 1 < g.nd && t >= g.d[d + 1].tile0) ++d;

    auto stage = [&](int dd, int tt, int ks, int pp) {
        const GD& D = g.d[dd];
        int local = tt - D.tile0;
        int m0 = (local / D.ntN) * 64;
        int n0 = (local % D.ntN) * 128;
        unsigned short* base = &ldsbuf[pp][0];
        {   // A: 64 rows, 4 issues total, 1 per wave
            int r0 = w * 16;
            int rowg = m0 + r0 + lrow;
            int mm = D.M - 1;
            rowg = rowg < mm ? rowg : mm;
            const char* src = (const char*)(D.A + (size_t)rowg * D.K + (ks << 5)) + schunk;
            GLOAD16(src, base + r0 * 32);
        }
#pragma unroll
        for (int ib = 0; ib < 2; ++ib) {  // B: 128 rows, 8 issues, 2 per wave
            int r0 = ib * 64 + w * 16;
            int rowg = n0 + r0 + lrow;
            const char* src = (const char*)(D.Bt + (size_t)rowg * D.K + (ks << 5)) + schunk;
            GLOAD16(src, base + 64 * 32 + r0 * 32);
        }
    };

    stage(d, t, 0, 0);
    int p = 0;

    while (true) {
        const GD D = g.d[d];
        int local = t - D.tile0;
        int m0 = (local / D.ntN) * 64;
        int n0 = (local % D.ntN) * 128;
        int nk = D.K >> 5;

        f32x4 acc[2][4];
#pragma unroll
        for (int i = 0; i < 2; ++i)
#pragma unroll
            for (int j = 0; j < 4; ++j) acc[i][j] = (f32x4){0.f, 0.f, 0.f, 0.f};

        for (int ks = 0; ks < nk; ++ks) {
            // stage next (k-step or next tile's first k-step)
            int nt = t, nks = ks + 1, ndd = d;
            bool have = true;
            if (nks == nk) {
                nt = t + gridDim.x; nks = 0;
                if (nt >= g.tot) have = false;
                else { while (ndd + 1 < g.nd && nt >= g.d[ndd + 1].tile0) ++ndd; }
            }
            if (have) { stage(ndd, nt, nks, p ^ 1); VMCNT(3); }
            else      { VMCNT(0); }
            __builtin_amdgcn_sched_barrier(0);
            __builtin_amdgcn_s_barrier();
            __builtin_amdgcn_sched_barrier(0);

            {   // compute from ldsbuf[p]
                const char* base = (const char*)&ldsbuf[p][0];
                bf16x8 af[2], bfr[4];
#pragma unroll
                for (int i = 0; i < 2; ++i) {
                    int row = wr * 32 + i * 16 + (l & 15);
                    af[i] = *(const bf16x8*)(base + row * 64 + rch);
                }
#pragma unroll
                for (int j = 0; j < 4; ++j) {
                    int row = wc * 64 + j * 16 + (l & 15);
                    bfr[j] = *(const bf16x8*)(base + 4096 + row * 64 + rch);
                }
#pragma unroll
                for (int i = 0; i < 2; ++i)
#pragma unroll
                    for (int j = 0; j < 4; ++j)
                        acc[i][j] = __builtin_amdgcn_mfma_f32_16x16x32_bf16(af[i], bfr[j], acc[i][j], 0, 0, 0);
            }
            __builtin_amdgcn_sched_barrier(0);
            __builtin_amdgcn_s_barrier();
            __builtin_amdgcn_sched_barrier(0);
            p ^= 1;
        }

        // epilogue
#pragma unroll
        for (int i = 0; i < 2; ++i) {
#pragma unroll
            for (int r = 0; r < 4; ++r) {
                int gm = m0 + wr * 32 + i * 16 + ((l >> 4) << 2) + r;
                if (gm >= D.M) continue;
#pragma unroll
                for (int j = 0; j < 4; ++j) {
                    int gn = n0 + wc * 64 + j * 16 + (l & 15);
                    float v = acc[i][j][r];
                    if (D.bias)  v += D.bias[gn];
                    if (D.resid) v += D.resid[(size_t)gm * D.N + gn];
                    if (D.act == 1)      v = fmaxf(v, 0.f);
                    else if (D.act == 2) v = 1.0f / (1.0f + __expf(-v));
                    if (D.outF) D.outF[(size_t)gm * D.N + gn] = v;
                    if (D.outB) D.outB[(size_t)gm * D.ldOutB + D.outBoff + gn] = f2b(v);
                }
            }
        }

        t += gridDim.x;
        if (t >= g.tot) break;
        while (d + 1 < g.nd && t >= g.d[d + 1].tile0) ++d;
    }
}

// ---------------------------------------------------------------------------
// Fused MFMA flash self-attention (unchanged from round 2, passed).
// ---------------------------------------------------------------------------
__global__ __launch_bounds__(256) void attn_mfma(
    const unsigned short* __restrict__ QK, const unsigned short* __restrict__ Vb,
    unsigned short* __restrict__ outB)
{
    const int qt = blockIdx.x;
    const int bh = blockIdx.y;
    const int b = bh >> 3, h = bh & 7;
    const int tid = threadIdx.x;
    const int w = tid >> 6, l = tid & 63;

    __shared__ __align__(16) unsigned short Ks[64 * 32];
    __shared__ __align__(16) unsigned short VT[32 * 64];
    __shared__ __align__(16) unsigned short Ps[4][64 * 20];

    const int qrow_w = qt * 64 + w * 16;
    int qr = qrow_w + (l & 15); qr = qr < LQ ? qr : LQ - 1;
    bf16x8 qf = *(const bf16x8*)(QK + ((size_t)(b * LQ + qr)) * 512 + h * 32 + (l >> 4) * 8);

    f32x4 acc0 = {0.f, 0.f, 0.f, 0.f}, acc1 = {0.f, 0.f, 0.f, 0.f};
    float m_run = -1e30f, l_run = 0.f;
    const float scale = 0.17677669529663689f;
    const f32x4 z4 = {0.f, 0.f, 0.f, 0.f};

    for (int kt = 0; kt < 15; ++kt) {
        __syncthreads();
        {
            int key = tid >> 2;
            int dg = (tid & 3) * 8;
            int krow = kt * 64 + key; krow = krow < LQ ? krow : LQ - 1;
            size_t base = (size_t)(b * LQ + krow);
            u16x8 kv = *(const u16x8*)(QK + base * 512 + 256 + h * 32 + dg);
            *(u16x8*)((char*)Ks + key * 64 + ((dg * 2) ^ ((key & 3) << 4))) = kv;
            u16x8 vv = *(const u16x8*)(Vb + base * 256 + h * 32 + dg);
#pragma unroll
            for (int e = 0; e < 8; ++e) {
                int dd = dg + e;
                *(unsigned short*)((char*)VT + dd * 128 + ((key * 2) ^ ((dd & 7) << 4))) = vv[e];
            }
        }
        __syncthreads();

        float p[4][4];
        float tmax = -1e30f;
#pragma unroll
        for (int m = 0; m < 4; ++m) {
            int kr = m * 16 + (l & 15);
            bf16x8 kf = *(const bf16x8*)((const char*)Ks + kr * 64 +
                        (((l >> 4) * 16) ^ ((kr & 3) << 4)));
            f32x4 sf = __builtin_amdgcn_mfma_f32_16x16x32_bf16(kf, qf, z4, 0, 0, 0);
#pragma unroll
            for (int r = 0; r < 4; ++r) {
                int key = kt * 64 + m * 16 + (l >> 4) * 4 + r;
                float sv = (key < LQ) ? sf[r] * scale : -1e30f;
                p[m][r] = sv;
                tmax = fmaxf(tmax, sv);
            }
        }
        tmax = fmaxf(tmax, __shfl_xor(tmax, 16, 64));
        tmax = fmaxf(tmax, __shfl_xor(tmax, 32, 64));
        float newm = fmaxf(m_run, tmax);
        float corr = __expf(m_run - newm);
        m_run = newm;
        float tsum = 0.f;
#pragma unroll
        for (int m = 0; m < 4; ++m)
#pragma unroll
            for (int r = 0; r < 4; ++r) {
                float e = __expf(p[m][r] - newm);
                p[m][r] = e;
                tsum += e;
            }
        tsum += __shfl_xor(tsum, 16, 64);
        tsum += __shfl_xor(tsum, 32, 64);
        l_run = l_run * corr + tsum;
        acc0 *= corr;
        acc1 *= corr;

        unsigned short* pw = &Ps[w][0];
#pragma unroll
        for (int m = 0; m < 4; ++m)
#pragma unroll
            for (int r = 0; r < 4; ++r) {
                int key = m * 16 + (l >> 4) * 4 + r;
                pw[key * 20 + (l & 15)] = f2b(p[m][r]);
            }

#pragma unroll
        for (int s = 0; s < 2; ++s) {
            union { unsigned short u[8]; bf16x8 v; } pb;
#pragma unroll
            for (int j = 0; j < 8; ++j)
                pb.u[j] = pw[(s * 32 + (l >> 4) * 8 + j) * 20 + (l & 15)];
#pragma unroll
            for (int m2 = 0; m2 < 2; ++m2) {
                int dd = m2 * 16 + (l & 15);
                bf16x8 vf = *(const bf16x8*)((const char*)VT + dd * 128 +
                            ((s * 64 + (l >> 4) * 16) ^ ((dd & 7) << 4)));
                if (m2 == 0) acc0 = __builtin_amdgcn_mfma_f32_16x16x32_bf16(vf, pb.v, acc0, 0, 0, 0);
                else         acc1 = __builtin_amdgcn_mfma_f32_16x16x32_bf16(vf, pb.v, acc1, 0, 0, 0);
            }
        }
    }

    float inv = 1.0f / l_run;
    int q = qrow_w + (l & 15);
    if (q < LQ) {
        size_t obase = ((size_t)(b * LQ + q)) * 256 + h * 32;
#pragma unroll
        for (int r = 0; r < 4; ++r) {
            int d0 = (l >> 4) * 4 + r;
            outB[obase + d0]      = f2b(acc0[r] * inv);
            outB[obase + 16 + d0] = f2b(acc1[r] * inv);
        }
    }
}

// ---------------------------------------------------------------------------
// Fused: sampling-weight softmax + locations + bilinear sampling.
// ---------------------------------------------------------------------------
__global__ __launch_bounds__(256) void sample_fused(
    const float* __restrict__ attl, const float* __restrict__ offf,
    const float* __restrict__ refp, const unsigned short* __restrict__ val,
    const int* __restrict__ shapes, const int* __restrict__ starts,
    float* __restrict__ aw_out, float* __restrict__ loc_out,
    unsigned short* __restrict__ samp, int NV)
{
    const int row = blockIdx.x;
    const int b = row / LQ;
    const int t = threadIdx.x;
    const int h = t >> 5, d = t & 31;

    __shared__ float l_logit[128];
    __shared__ float l_aw[128];
    __shared__ float l_loc[256];
    __shared__ int l_sh[NL * 2];
    __shared__ int l_st[NL];

    if (t < 128) l_logit[t] = attl[(size_t)row * 128 + t];
    {
        float o = offf[(size_t)row * 256 + t];
        int c = t & 1;
        int lv = (t >> 3) & 3;
        float rc = refp[((size_t)row * 4 + lv) * 4 + c];
        float rs = refp[((size_t)row * 4 + lv) * 4 + 2 + c];
        float loc = rc + o * 0.125f * rs;
        l_loc[t] = loc;
        loc_out[(size_t)row * 256 + t] = loc;
    }
    if (t < NL * 2) l_sh[t] = shapes[t];
    if (t < NL) l_st[t] = starts[t];
    __syncthreads();
    if (t < 128) {
        int hh = t >> 4;
        float mx = -1e30f;
#pragma unroll
        for (int i = 0; i < 16; ++i) mx = fmaxf(mx, l_logit[hh * 16 + i]);
        float sum = 0.f;
#pragma unroll
        for (int i = 0; i < 16; ++i) sum += __expf(l_logit[hh * 16 + i] - mx);
        float aw = __expf(l_logit[t] - mx) / sum;
        l_aw[t] = aw;
        aw_out[(size_t)row * 128 + t] = aw;
    }
    __syncthreads();

    float acc = 0.f;
    const unsigned short* vb = val + (size_t)b * NV * EE + h * HD + d;

#pragma unroll
    for (int lv = 0; lv < NL; ++lv) {
        const int Hh = l_sh[lv * 2], Ww = l_sh[lv * 2 + 1];
        const int s0 = l_st[lv];
#pragma unroll
        for (int p = 0; p < NP; ++p) {
            const int base = ((h * NL + lv) * NP + p) * 2;
            float lx = l_loc[base], ly = l_loc[base + 1];
            float wgt0 = l_aw[h * 16 + lv * NP + p];
            float px = lx * (float)Ww - 0.5f;
            float py = ly * (float)Hh - 0.5f;
            float x0f = floorf(px), y0f = floorf(py);
            float wx = px - x0f, wy = py - y0f;
            int x0 = (int)x0f, y0 = (int)y0f;
#pragma unroll
            for (int dy = 0; dy < 2; ++dy) {
                int yi = y0 + dy;
                bool vy = (yi >= 0) && (yi < Hh);
                int yc = min(max(yi, 0), Hh - 1);
                float wyv = dy ? wy : 1.f - wy;
#pragma unroll
                for (int dx = 0; dx < 2; ++dx) {
                    int xi = x0 + dx;
                    bool vv = vy && (xi >= 0) && (xi < Ww);
                    int xc = min(max(xi, 0), Ww - 1);
                    float wgt = wgt0 * wyv * (dx ? wx : 1.f - wx);
                    float gv = b2f(vb[(size_t)(s0 + yc * Ww + xc) * EE]);
                    acc += vv ? wgt * gv : 0.f;
                }
            }
        }
    }
    samp[(size_t)row * EE + t] = f2b(acc);
}

// ---------------------------------------------------------------------------
// Gated fusion + ln3: x2 = g1*x1 + g2*cross; z_b = bf16(ln3(x2))
// ---------------------------------------------------------------------------
__global__ __launch_bounds__(256) void gate_ln3(
    const float* __restrict__ g, const float* __restrict__ x1,
    const float* __restrict__ cross, const float* __restrict__ s,
    const float* __restrict__ bln, float* __restrict__ x2out,
    unsigned short* __restrict__ zb)
{
    const int row = blockIdx.x;
    const int t = threadIdx.x;
    const int w = t >> 6;
    const int lane = t & 63;
    __shared__ float red[4];

    float g1 = g[(size_t)row * 512 + t];
    float g2 = g[(size_t)row * 512 + 256 + t];
    float v = g1 * x1[(size_t)row * EE + t] + g2 * cross[(size_t)row * EE + t];
    x2out[(size_t)row * EE + t] = v;

    float sum = v;
#pragma unroll
    for (int o = 32; o; o >>= 1) sum += __shfl_xor(sum, o, 64);
    if (lane == 0) red[w] = sum;
    __syncthreads();
    float mean = (red[0] + red[1] + red[2] + red[3]) * (1.0f / 256.0f);
    __syncthreads();

    float d = v - mean;
    float sq = d * d;
#pragma unroll
    for (int o = 32; o; o >>= 1) sq += __shfl_xor(sq, o, 64);
    if (lane == 0) red[w] = sq;
    __syncthreads();
    float var = (red[0] + red[1] + red[2] + red[3]) * (1.0f / 256.0f);

    float y = d * rsqrtf(var + 1e-5f) * s[t] + bln[t];
    zb[(size_t)row * EE + t] = f2b(y);
}

// ---------------------------------------------------------------------------
extern "C" void kernel_launch(void* const* d_in, const int* in_sizes, int n_in,
                              void* d_out, int out_size, void* d_ws, size_t ws_size,
                              hipStream_t stream)
{
    const float* queries   = (const float*)d_in[0];
    const float* memory    = (const float*)d_in[1];
    const float* query_pos = (const float*)d_in[2];
    const float* refp      = (const float*)d_in[3];
    const int*   shapes    = (const int*)d_in[4];
    const int*   starts    = (const int*)d_in[5];
    const float* Wq  = (const float*)d_in[6],  *bq  = (const float*)d_in[7];
    const float* Wk  = (const float*)d_in[8],  *bk  = (const float*)d_in[9];
    const float* Wv  = (const float*)d_in[10], *bv  = (const float*)d_in[11];
    const float* Wo  = (const float*)d_in[12], *bo  = (const float*)d_in[13];
    const float* Wvd = (const float*)d_in[14], *bvd = (const float*)d_in[15];
    const float* Woff= (const float*)d_in[16], *boff= (const float*)d_in[17];
    const float* Watt= (const float*)d_in[18], *batt= (const float*)d_in[19];
    const float* Wop = (const float*)d_in[20], *bop = (const float*)d_in[21];
    const float* Wg  = (const float*)d_in[22], *bg  = (const float*)d_in[23];
    const float* W1  = (const float*)d_in[24], *b1  = (const float*)d_in[25];
    const float* W2  = (const float*)d_in[26], *b2  = (const float*)d_in[27];
    const float* ln1_s = (const float*)d_in[28], *ln1_b = (const float*)d_in[29];
    const float* ln2_s = (const float*)d_in[30], *ln2_b = (const float*)d_in[31];
    const float* ln3_s = (const float*)d_in[32], *ln3_b = (const float*)d_in[33];

    const int NV = in_sizes[1] / (BB * EE);   // 13294
    const int Mq = BB * LQ;                   // 7200
    const long memN = (long)BB * NV * EE;     // 27,226,112

    char* W8 = (char*)d_ws;
    size_t off = 0;
    auto alloc = [&](size_t bytes) { char* p = W8 + off; off += (bytes + 255) & ~(size_t)255; return p; };

    unsigned short* mem_b = (unsigned short*)alloc((size_t)memN * 2);  // reused later
    unsigned short* val_b = (unsigned short*)alloc((size_t)memN * 2);
    unsigned short* WtQK  = (unsigned short*)alloc(512 * 256 * 2);
    unsigned short* WtV   = (unsigned short*)alloc(256 * 256 * 2);
    unsigned short* WtO   = (unsigned short*)alloc(256 * 256 * 2);
    unsigned short* WtVD  = (unsigned short*)alloc(256 * 256 * 2);
    unsigned short* WtOFF = (unsigned short*)alloc(256 * 256 * 2);
    unsigned short* WtATT = (unsigned short*)alloc(128 * 256 * 2);
    unsigned short* WtOP  = (unsigned short*)alloc(256 * 256 * 2);
    unsigned short* WtG   = (unsigned short*)alloc(512 * 512 * 2);
    unsigned short* Wt1   = (unsigned short*)alloc(1024 * 256 * 2);
    unsigned short* Wt2   = (unsigned short*)alloc(256 * 1024 * 2);
    float*          bqk   = (float*)alloc(512 * 4);
    unsigned short* qkb   = (unsigned short*)alloc((size_t)Mq * 512 * 2);  // -> off_f (f32 [Mq][256])
    unsigned short* vb_buf= (unsigned short*)alloc((size_t)Mq * 256 * 2);  // -> attl (f32 [Mq][128])
    unsigned short* av_buf= (unsigned short*)alloc((size_t)Mq * 256 * 2);  // -> samp_b
    float*          x1    = (float*)alloc((size_t)Mq * 256 * 4);
    unsigned short* xc_cat= (unsigned short*)alloc((size_t)Mq * 512 * 2);
    unsigned short* qc_b  = (unsigned short*)alloc((size_t)Mq * 256 * 2);
    float*          cross = (float*)alloc((size_t)Mq * 256 * 4);           // early: x_b|qk_b

    // aliases
    unsigned short* x_b  = (unsigned short*)cross;                 // consumed by launch 5
    unsigned short* qk_b = x_b + (size_t)Mq * 256;
    float* off_f = (float*)qkb;            // after attn
    float* attl  = (float*)vb_buf;         // after attn
    unsigned short* samp_b = av_buf;       // after Wo
    // mem_b region reuse (after val GEMM):
    float* gbuf = (float*)mem_b;                                   // [Mq][512] f32
    float* x2   = (float*)((char*)mem_b + (size_t)Mq * 512 * 4);
    unsigned short* z_b = (unsigned short*)((char*)x2 + (size_t)Mq * 256 * 4);
    unsigned short* hidden_b = (unsigned short*)((char*)z_b + (size_t)Mq * 256 * 2);

    float* out0    = (float*)d_out;
    float* aw_out  = out0 + (size_t)Mq * 256;
    float* loc_out = aw_out + (size_t)Mq * 128;

    dim3 blk(256);

    // 1-3. weight prep + memory cast
    TPack tp;
    tp.d[0]  = { Wq,   WtQK,             256, 256,    0 };
    tp.d[1]  = { Wk,   WtQK + 256 * 256, 256, 256,   64 };
    tp.d[2]  = { Wv,   WtV,              256, 256,  128 };
    tp.d[3]  = { Wo,   WtO,              256, 256,  192 };
    tp.d[4]  = { Wvd,  WtVD,             256, 256,  256 };
    tp.d[5]  = { Woff, WtOFF,            256, 256,  320 };
    tp.d[6]  = { Watt, WtATT,            256, 128,  384 };
    tp.d[7]  = { Wop,  WtOP,             256, 256,  416 };
    tp.d[8]  = { Wg,   WtG,              512, 512,  480 };
    tp.d[9]  = { W1,   Wt1,              256, 1024, 736 };
    tp.d[10] = { W2,   Wt2,             1024, 256,  992 };
    trans_kernel<<<1248, blk, 0, stream>>>(tp);
    bcat_kernel<<<2, blk, 0, stream>>>(bq, bk, bqk);
    cast_kernel<<<2048, blk, 0, stream>>>(memory, mem_b, memN);

    // 4. ln1
    ln_bf<<<Mq, blk, 0, stream>>>(queries, ln1_s, ln1_b, query_pos, x_b, qk_b);

    // 5. batched {VAL, QK, V}
    {
        GB g; g.nd = 3;
        int ntM_val = (BB * NV + 63) / 64;   // 1662
        int t0 = 0;
        g.d[0] = { mem_b, WtVD, bvd, nullptr, nullptr, val_b,  BB * NV, 256, 256, 2, t0, 256, 0, 0 };
        t0 += ntM_val * 2;
        g.d[1] = { qk_b,  WtQK, bqk, nullptr, nullptr, qkb,    Mq,      256, 512, 4, t0, 512, 0, 0 };
        t0 += 113 * 4;
        g.d[2] = { x_b,   WtV,  bv,  nullptr, nullptr, vb_buf, Mq,      256, 256, 2, t0, 256, 0, 0 };
        t0 += 113 * 2;
        g.tot = t0;
        gemm_pipe<<<1536, blk, 0, stream>>>(g);
    }

    // 6. self-attention
    attn_mfma<<<dim3(15, BB * NH), blk, 0, stream>>>(qkb, vb_buf, av_buf);

    // 7. x1 = attnV @ Wo + bo + queries  (fp32 + bf16 into cat buffer)
    {
        GB g; g.nd = 1;
        g.d[0] = { av_buf, WtO, bo, queries, x1, xc_cat, Mq, 256, 256, 2, 0, 512, 0, 0 };
        g.tot = 113 * 2;
        gemm_pipe<<<g.tot, blk, 0, stream>>>(g);
    }

    // 8. qc = ln2(x1) + pos
    ln_bf<<<Mq, blk, 0, stream>>>(x1, ln2_s, ln2_b, query_pos, nullptr, qc_b);

    // 9. batched {OFF, ATT}
    {
        GB g; g.nd = 2;
        g.d[0] = { qc_b, WtOFF, boff, nullptr, off_f, nullptr, Mq, 256, 256, 2, 0,       256, 0, 0 };
        g.d[1] = { qc_b, WtATT, batt, nullptr, attl,  nullptr, Mq, 256, 128, 1, 113 * 2, 128, 0, 0 };
        g.tot = 113 * 3;
        gemm_pipe<<<g.tot, blk, 0, stream>>>(g);
    }

    // 10. softmax + loc + bilinear sampling
    sample_fused<<<Mq, blk, 0, stream>>>(attl, off_f, refp, val_b, shapes, starts,
                                         aw_out, loc_out, samp_b, NV);

    // 11. cross = samp @ Wop + bop (fp32 + bf16 into cat cols 256-511)
    {
        GB g; g.nd = 1;
        g.d[0] = { samp_b, WtOP, bop, nullptr, cross, xc_cat, Mq, 256, 256, 2, 0, 512, 256, 0 };
        g.tot = 113 * 2;
        gemm_pipe<<<g.tot, blk, 0, stream>>>(g);
    }

    // 12. g = sigmoid([x1|cross] @ Wg + bg)
    {
        GB g; g.nd = 1;
        g.d[0] = { xc_cat, WtG, bg, nullptr, gbuf, nullptr, Mq, 512, 512, 4, 0, 512, 0, 2 };
        g.tot = 113 * 4;
        gemm_pipe<<<g.tot, blk, 0, stream>>>(g);
    }

    // 13. x2 + ln3
    gate_ln3<<<Mq, blk, 0, stream>>>(gbuf, x1, cross, ln3_s, ln3_b, x2, z_b);

    // 14. hidden = relu(z @ W1 + b1)
    {
        GB g; g.nd = 1;
        g.d[0] = { z_b, Wt1, b1, nullptr, nullptr, hidden_b, Mq, 256, 1024, 8, 0, 1024, 0, 1 };
        g.tot = 113 * 8;
        gemm_pipe<<<g.tot, blk, 0, stream>>>(g);
    }

    // 15. out0 = hidden @ W2 + b2 + x2
    {
        GB g; g.nd = 1;
        g.d[0] = { hidden_b, Wt2, b2, x2, out0, nullptr, Mq, 1024, 256, 2, 0, 256, 0, 0 };
        g.tot = 113 * 2;
        gemm_pipe<<<g.tot, blk, 0, stream>>>(g);
    }
}